// Round 14
// baseline (72.835 us; speedup 1.0000x reference)
//
#include <hip/hip_runtime.h>
#include <stdint.h>

typedef __attribute__((ext_vector_type(8))) short bf16x8;
typedef __attribute__((ext_vector_type(8))) unsigned short u16x8;
typedef __attribute__((ext_vector_type(4))) float f32x4;
typedef unsigned short u16;

constexpr int NN = 2048, NF = 256;

__device__ inline u16 f2bf(float f) {
  uint32_t u = __builtin_bit_cast(uint32_t, f);
  uint32_t r = (u + 0x7FFFu + ((u >> 16) & 1u)) >> 16;
  return (u16)r;
}
__device__ inline float bf2f(u16 h) {
  uint32_t u = ((uint32_t)h) << 16;
  return __builtin_bit_cast(float, u);
}

__device__ inline void gload_lds16(const void* g, void* l) {
  __builtin_amdgcn_global_load_lds(
      (const __attribute__((address_space(1))) uint32_t*)g,
      (__attribute__((address_space(3))) uint32_t*)l,
      16, 0, 0);
}

// ---- K1: d[row]=rsqrt(1+sum adj[row,:]); tail blocks: Wconv ----------------
__global__ __launch_bounds__(256) void k_rowsum(const float* __restrict__ adj,
                                                float* __restrict__ d,
                                                const float* __restrict__ W,
                                                u16* __restrict__ Wb) {
  if (blockIdx.x >= 16384) {
    int i = (blockIdx.x - 16384) * 256 + threadIdx.x;
    float4 v = ((const float4*)W)[i];
    ushort4 o;
    o.x = f2bf(v.x); o.y = f2bf(v.y); o.z = f2bf(v.z); o.w = f2bf(v.w);
    *(ushort4*)(Wb + (size_t)i * 4) = o;
    return;
  }
  int row = blockIdx.x;
  const float4* p = (const float4*)(adj + (size_t)row * NN);
  float s = 0.f;
#pragma unroll
  for (int c = 0; c < 2; ++c) {
    float4 v = p[threadIdx.x + 256 * c];
    s += v.x + v.y + v.z + v.w;
  }
#pragma unroll
  for (int off = 32; off > 0; off >>= 1) s += __shfl_down(s, off, 64);
  __shared__ float red[4];
  int lane = threadIdx.x & 63, w = threadIdx.x >> 6;
  if (lane == 0) red[w] = s;
  __syncthreads();
  if (threadIdx.x == 0) {
    float t = red[0] + red[1] + red[2] + red[3] + 1.0f;
    d[row] = 1.0f / sqrtf(t);
  }
}

// ---- K2: XpT[b,f,j] = bf16(d_j * X[b,j,f])  (plain transpose) --------------
__global__ __launch_bounds__(256) void k_xprep(const float* __restrict__ X,
                                               const float* __restrict__ d,
                                               u16* __restrict__ XpT) {
  int jt = blockIdx.x, ft = blockIdx.y, b = blockIdx.z;
  int j0 = jt * 64, f0 = ft * 64;
  __shared__ u16 T[64][66];
  int t = threadIdx.x;
#pragma unroll
  for (int s = 0; s < 4; ++s) {
    int q = s * 256 + t;
    int r = q >> 4, c4 = q & 15;
    int j = j0 + r;
    float dv = d[b * NN + j];
    float4 v = *(const float4*)(X + ((size_t)(b * NN + j)) * NF + f0 + c4 * 4);
    T[r][c4 * 4 + 0] = f2bf(v.x * dv);
    T[r][c4 * 4 + 1] = f2bf(v.y * dv);
    T[r][c4 * 4 + 2] = f2bf(v.z * dv);
    T[r][c4 * 4 + 3] = f2bf(v.w * dv);
  }
  __syncthreads();
#pragma unroll
  for (int s = 0; s < 4; ++s) {
    int q = s * 256 + t;
    int fr = q >> 4, c4 = q & 15;
    ushort4 o;
    o.x = T[c4 * 4 + 0][fr]; o.y = T[c4 * 4 + 1][fr];
    o.z = T[c4 * 4 + 2][fr]; o.w = T[c4 * 4 + 3][fr];
    *(ushort4*)(XpT + ((size_t)(b * NF + f0 + fr)) * NN + j0 + c4 * 4) = o;
  }
}

// ---- Fused: H = d_i*(adj@Xp + Xp_i) ; out = relu(H@W^T + bias) -------------
// BM=64, BN=256, BK=64/window (32 windows), 512 thr (8 waves), 1 blk/CU.
// K-parity split: wave (wr,wc) computes the FULL 64x64 tile for col-stripe wc,
// accumulating only K-substep parity wr. acc[4][4]; partials summed in epi1.
// Staging identical to R13: A fp32->regs->cvt->ds (3x8K mod-3); B glds (3x32K).
#define BBASE 24576

// Step KS (window of 64 k-cols). R3 = KS%3 (read slot), W3 = (KS+2)%3 (write).
#define STEP(KS, R3, W3, VMC, IA, WA, IB)                                      \
  {                                                                            \
    if (IB) {                                                                  \
      gload_lds16(b_src0 + (size_t)((KS) + 2) * 64,                            \
                  smem + BBASE + (W3) * 32768 + bw0);                          \
      gload_lds16(b_src1 + (size_t)((KS) + 2) * 64,                            \
                  smem + BBASE + (W3) * 32768 + bw1);                          \
      gload_lds16(b_src0 + (size_t)((KS) + 2) * 64 + 32,                       \
                  smem + BBASE + (W3) * 32768 + 16384 + bw0);                  \
      gload_lds16(b_src1 + (size_t)((KS) + 2) * 64 + 32,                       \
                  smem + BBASE + (W3) * 32768 + 16384 + bw1);                  \
    }                                                                          \
    if (IA) {                                                                  \
      aN0[R3] = *(const float4*)(a_gsrc + (size_t)((KS) + 3) * 64);            \
      aN1[R3] = *(const float4*)(a_gsrc + (size_t)((KS) + 3) * 64 + 4);        \
    }                                                                          \
    __builtin_amdgcn_sched_barrier(0);                                         \
    asm volatile("s_waitcnt vmcnt(" VMC ") lgkmcnt(0)" ::: "memory");          \
    __builtin_amdgcn_sched_barrier(0);                                         \
    __builtin_amdgcn_s_barrier();                                              \
    __builtin_amdgcn_sched_barrier(0);                                         \
    const char* Ab = smem + (R3) * 8192 + awrh;                                \
    const char* Bb = smem + BBASE + (R3) * 32768 + bwrh;                       \
    bf16x8 af0 = *(const bf16x8*)(Ab + aoff0);                                 \
    bf16x8 bf0 = *(const bf16x8*)(Bb + boff0);                                 \
    bf16x8 bf1 = *(const bf16x8*)(Bb + boff0 + 1024);                          \
    bf16x8 bf2 = *(const bf16x8*)(Bb + boff0 + 2048);                          \
    bf16x8 bf3 = *(const bf16x8*)(Bb + boff0 + 3072);                          \
    bf16x8 af1 = *(const bf16x8*)(Ab + aoff0 + 1024);                          \
    bf16x8 af2 = *(const bf16x8*)(Ab + aoff0 + 2048);                          \
    bf16x8 af3 = *(const bf16x8*)(Ab + aoff0 + 3072);                          \
    asm volatile("s_waitcnt lgkmcnt(3)" ::: "memory");                         \
    __builtin_amdgcn_sched_barrier(0);                                         \
    __builtin_amdgcn_s_setprio(1);                                             \
    acc[0][0] = __builtin_amdgcn_mfma_f32_16x16x32_bf16(af0, bf0, acc[0][0], 0, 0, 0); \
    acc[0][1] = __builtin_amdgcn_mfma_f32_16x16x32_bf16(af0, bf1, acc[0][1], 0, 0, 0); \
    acc[0][2] = __builtin_amdgcn_mfma_f32_16x16x32_bf16(af0, bf2, acc[0][2], 0, 0, 0); \
    acc[0][3] = __builtin_amdgcn_mfma_f32_16x16x32_bf16(af0, bf3, acc[0][3], 0, 0, 0); \
    __builtin_amdgcn_s_setprio(0);                                             \
    __builtin_amdgcn_sched_barrier(0);                                         \
    asm volatile("s_waitcnt lgkmcnt(0)" ::: "memory");                         \
    __builtin_amdgcn_sched_barrier(0);                                         \
    __builtin_amdgcn_s_setprio(1);                                             \
    acc[1][0] = __builtin_amdgcn_mfma_f32_16x16x32_bf16(af1, bf0, acc[1][0], 0, 0, 0); \
    acc[1][1] = __builtin_amdgcn_mfma_f32_16x16x32_bf16(af1, bf1, acc[1][1], 0, 0, 0); \
    acc[1][2] = __builtin_amdgcn_mfma_f32_16x16x32_bf16(af1, bf2, acc[1][2], 0, 0, 0); \
    acc[1][3] = __builtin_amdgcn_mfma_f32_16x16x32_bf16(af1, bf3, acc[1][3], 0, 0, 0); \
    acc[2][0] = __builtin_amdgcn_mfma_f32_16x16x32_bf16(af2, bf0, acc[2][0], 0, 0, 0); \
    acc[2][1] = __builtin_amdgcn_mfma_f32_16x16x32_bf16(af2, bf1, acc[2][1], 0, 0, 0); \
    acc[2][2] = __builtin_amdgcn_mfma_f32_16x16x32_bf16(af2, bf2, acc[2][2], 0, 0, 0); \
    acc[2][3] = __builtin_amdgcn_mfma_f32_16x16x32_bf16(af2, bf3, acc[2][3], 0, 0, 0); \
    acc[3][0] = __builtin_amdgcn_mfma_f32_16x16x32_bf16(af3, bf0, acc[3][0], 0, 0, 0); \
    acc[3][1] = __builtin_amdgcn_mfma_f32_16x16x32_bf16(af3, bf1, acc[3][1], 0, 0, 0); \
    acc[3][2] = __builtin_amdgcn_mfma_f32_16x16x32_bf16(af3, bf2, acc[3][2], 0, 0, 0); \
    acc[3][3] = __builtin_amdgcn_mfma_f32_16x16x32_bf16(af3, bf3, acc[3][3], 0, 0, 0); \
    __builtin_amdgcn_s_setprio(0);                                             \
    __builtin_amdgcn_sched_barrier(0);                                         \
    if (WA) {                                                                  \
      float4 c0 = aN0[W3], c1 = aN1[W3];                                       \
      u16x8 pk;                                                                \
      pk[0] = f2bf(c0.x); pk[1] = f2bf(c0.y); pk[2] = f2bf(c0.z);              \
      pk[3] = f2bf(c0.w); pk[4] = f2bf(c1.x); pk[5] = f2bf(c1.y);              \
      pk[6] = f2bf(c1.z); pk[7] = f2bf(c1.w);                                  \
      *(u16x8*)(smem + (W3) * 8192 + a_ldst) = pk;                             \
    }                                                                          \
    __builtin_amdgcn_sched_barrier(0);                                         \
  }

__global__ __launch_bounds__(512, 2) void k_fused(
    const float* __restrict__ adj, const u16* __restrict__ XpT,
    const float* __restrict__ dsc, const u16* __restrict__ Wb,
    const float* __restrict__ bias, float* __restrict__ out) {
  int flat = blockIdx.x;
  int b = flat & 7, mt = flat >> 3;  // batch->XCD affinity
  int i0 = mt * 64;

  __shared__ __align__(16) char smem[122880];  // A 3x8K | B 3x32K ; epi aliases
  float* Hsf = (float*)smem;                   // [64][260] f32 partials
  u16* HsBf = (u16*)(smem + 66560);            // [64][264] bf16 H

  int t = threadIdx.x;
  int lane = t & 63, w = t >> 6;
  int l15 = lane & 15, l4 = lane >> 4;
  int wr = w >> 2, wc = w & 3;

  const float* adjf = adj + ((size_t)b * NN + i0) * NN;
  const u16* XpTb = XpT + (size_t)b * NF * NN;

  // A staging: thread t -> row rA=t>>3, 8-float chunk kc=t&7 within 64-k window
  int rA = t >> 3, kc = t & 7;
  const float* a_gsrc = adjf + (size_t)rA * NN + kc * 8;
  int a_ldst = (kc >> 2) * 4096 + rA * 64 + (((kc & 3) ^ ((rA >> 1) & 3)) << 4);

  // B staging (glds, source-swizzled): slots t and t+512 of [256][32] per half
  int n0s = t >> 2, c0s = t & 3;
  const u16* b_src0 = XpTb + (size_t)n0s * NN + ((c0s ^ ((n0s >> 1) & 3)) << 3);
  int s1 = 512 + t;
  int n1s = s1 >> 2, c1s = s1 & 3;
  const u16* b_src1 = XpTb + (size_t)n1s * NN + ((c1s ^ ((n1s >> 1) & 3)) << 3);
  int bw0 = w << 10;
  int bw1 = 8192 + (w << 10);

  // frag read byte offsets; wr selects the K-parity half of each buffer
  int swz = (l4 ^ ((l15 >> 1) & 3)) << 4;
  int aoff0 = l15 * 64 + swz;
  int boff0 = (wc * 64 + l15) * 64 + swz;
  int awrh = wr * 4096;
  int bwrh = wr * 16384;

  f32x4 acc[4][4] = {};
  float4 aN0[3], aN1[3];

  // ---- prologue: A windows 0,1 -> granules 0,1; B windows 0,1 -> bufs 0,1;
  //      A window 2 -> reg set 2 ----
  {
    float4 p0a = *(const float4*)(a_gsrc);
    float4 p0b = *(const float4*)(a_gsrc + 4);
    float4 p1a = *(const float4*)(a_gsrc + 64);
    float4 p1b = *(const float4*)(a_gsrc + 68);
    __builtin_amdgcn_sched_barrier(0);
    gload_lds16(b_src0, smem + BBASE + bw0);
    gload_lds16(b_src1, smem + BBASE + bw1);
    gload_lds16(b_src0 + 32, smem + BBASE + 16384 + bw0);
    gload_lds16(b_src1 + 32, smem + BBASE + 16384 + bw1);
    gload_lds16(b_src0 + 64, smem + BBASE + 32768 + bw0);
    gload_lds16(b_src1 + 64, smem + BBASE + 32768 + bw1);
    gload_lds16(b_src0 + 96, smem + BBASE + 32768 + 16384 + bw0);
    gload_lds16(b_src1 + 96, smem + BBASE + 32768 + 16384 + bw1);
    __builtin_amdgcn_sched_barrier(0);
    aN0[2] = *(const float4*)(a_gsrc + 128);  // window 2 -> set 2
    aN1[2] = *(const float4*)(a_gsrc + 132);
    __builtin_amdgcn_sched_barrier(0);
    u16x8 pk;
    pk[0] = f2bf(p0a.x); pk[1] = f2bf(p0a.y); pk[2] = f2bf(p0a.z);
    pk[3] = f2bf(p0a.w); pk[4] = f2bf(p0b.x); pk[5] = f2bf(p0b.y);
    pk[6] = f2bf(p0b.z); pk[7] = f2bf(p0b.w);
    *(u16x8*)(smem + a_ldst) = pk;            // granule 0
    pk[0] = f2bf(p1a.x); pk[1] = f2bf(p1a.y); pk[2] = f2bf(p1a.z);
    pk[3] = f2bf(p1a.w); pk[4] = f2bf(p1b.x); pk[5] = f2bf(p1b.y);
    pk[6] = f2bf(p1b.z); pk[7] = f2bf(p1b.w);
    *(u16x8*)(smem + 8192 + a_ldst) = pk;     // granule 1
    __builtin_amdgcn_sched_barrier(0);
  }

  // ---- windows 0,1 peeled (prologue-adjusted vmcnt) ----
  STEP(0, 0, 2, "10", 1, 1, 1)
  STEP(1, 1, 0, "12", 1, 1, 1)
  // ---- main loop: windows 2..25 (8 x 3, period-3 literals) ----
  for (int sb = 2; sb <= 23; sb += 3) {
    STEP(sb + 0, 2, 1, "12", 1, 1, 1)
    STEP(sb + 1, 0, 2, "12", 1, 1, 1)
    STEP(sb + 2, 1, 0, "12", 1, 1, 1)
  }
  // ---- tail: windows 26..31 ----
  STEP(26, 2, 1, "12", 1, 1, 1)
  STEP(27, 0, 2, "12", 1, 1, 1)
  STEP(28, 1, 0, "12", 1, 1, 1)
  STEP(29, 2, 1, "12", 0, 1, 1)
  STEP(30, 0, 2, "4", 0, 0, 0)
  STEP(31, 1, 0, "0", 0, 0, 0)

  __syncthreads();  // drain all before epi aliases staging buffers

  // ---- epilogue 1a: wr=1 waves park their K-odd partials in LDS (f32) ----
  if (wr == 1) {
#pragma unroll
    for (int mi = 0; mi < 4; ++mi)
#pragma unroll
      for (int ni = 0; ni < 4; ++ni) {
        int f = wc * 64 + ni * 16 + l15;
#pragma unroll
        for (int qq = 0; qq < 4; ++qq) {
          int il = mi * 16 + l4 * 4 + qq;
          Hsf[il * 260 + f] = acc[mi][ni][qq];
        }
      }
  }
  __syncthreads();

  // ---- epilogue 1b: wr=0 waves combine + I-term + d-scale -> bf16 H ----
  const float* db = dsc + b * NN;
  if (wr == 0) {
#pragma unroll
    for (int mi = 0; mi < 4; ++mi) {
#pragma unroll
      for (int ni = 0; ni < 4; ++ni) {
        int f = wc * 64 + ni * 16 + l15;
        ushort4 xv = *(const ushort4*)(XpTb + (size_t)f * NN + i0 +
                                       mi * 16 + l4 * 4);
#pragma unroll
        for (int qq = 0; qq < 4; ++qq) {
          int il = mi * 16 + l4 * 4 + qq;
          float dv = db[i0 + il];
          float part = acc[mi][ni][qq] + Hsf[il * 260 + f];
          float hv = dv * (part + bf2f(((const u16*)&xv)[qq]));
          HsBf[il * 264 + f] = f2bf(hv);
        }
      }
    }
  }
  __syncthreads();

  // ---- epilogue 2: out = relu(H @ W^T + bias), W frags from L2 ----
  f32x4 acc2[2][4] = {};
#pragma unroll
  for (int kk = 0; kk < 256; kk += 32) {
    bf16x8 a2[2], b2[4];
#pragma unroll
    for (int mi = 0; mi < 2; ++mi) {
      int r = wr * 32 + mi * 16 + l15;
      a2[mi] = *(const bf16x8*)&HsBf[r * 264 + kk + l4 * 8];
    }
#pragma unroll
    for (int ni = 0; ni < 4; ++ni) {
      int o = wc * 64 + ni * 16 + l15;
      b2[ni] = *(const bf16x8*)&Wb[(size_t)o * 256 + kk + l4 * 8];
    }
#pragma unroll
    for (int mi = 0; mi < 2; ++mi)
#pragma unroll
      for (int ni = 0; ni < 4; ++ni)
        acc2[mi][ni] = __builtin_amdgcn_mfma_f32_16x16x32_bf16(a2[mi], b2[ni],
                                                               acc2[mi][ni], 0, 0, 0);
  }

  float* outb = out + ((size_t)b * NN + i0) * NF;
#pragma unroll
  for (int mi = 0; mi < 2; ++mi) {
#pragma unroll
    for (int qq = 0; qq < 4; ++qq) {
      int il = wr * 32 + mi * 16 + l4 * 4 + qq;
#pragma unroll
      for (int ni = 0; ni < 4; ++ni) {
        int o = wc * 64 + ni * 16 + l15;
        float v = acc2[mi][ni][qq] + bias[o];
        outb[(size_t)il * NF + o] = fmaxf(v, 0.f);
      }
    }
  }
}

extern "C" void kernel_launch(void* const* d_in, const int* in_sizes, int n_in,
                              void* d_out, int out_size, void* d_ws, size_t ws_size,
                              hipStream_t stream) {
  const float* X    = (const float*)d_in[0];
  const float* adj  = (const float*)d_in[1];
  const float* W    = (const float*)d_in[2];
  const float* bias = (const float*)d_in[3];
  float* out = (float*)d_out;

  char* ws = (char*)d_ws;
  float* dsc = (float*)(ws);                 // 64 KB
  u16*   Wb  = (u16*)(ws + 65536);           // 128 KB
  u16*   XpT = (u16*)(ws + 262144);          // 8 MB

  k_rowsum<<<dim3(16448), dim3(256), 0, stream>>>(adj, dsc, W, Wb);
  k_xprep<<<dim3(32, 4, 8), dim3(256), 0, stream>>>(X, dsc, XpT);
  k_fused<<<dim3(256), dim3(512), 0, stream>>>(adj, XpT, dsc, Wb, bias, out);
}